// Round 5
// baseline (116.026 us; speedup 1.0000x reference)
//
#include <hip/hip_runtime.h>
#include <hip/hip_bf16.h>
#include <stdint.h>

typedef short bf16x8 __attribute__((ext_vector_type(8)));
typedef short short8 __attribute__((ext_vector_type(8)));
typedef float f32x4 __attribute__((ext_vector_type(4)));

#define B_   64
#define NQ   32
#define ND   256
#define DIM  128
#define MT   4          // bq per MFMA group
#define NEG_INF_F (-1.0e9f)
#define VALID_F   (-1.0e8f)

// ---------------- Kernel 1: L2-normalize Q rows only, mask, emit bf16 (linear) -------
// 16 lanes per row, 16 rows per 256-thread block, 128 blocks.
__global__ __launch_bounds__(256) void qnorm(
    const float* __restrict__ q, const int* __restrict__ qmask,
    __hip_bfloat16* __restrict__ qn)
{
    const int tid = threadIdx.x;
    const int sub = tid & 15;
    const int row = blockIdx.x * 16 + (tid >> 4);   // 0 .. 2047

    const float* src = q + (size_t)row * DIM;
    const float4 v0 = *reinterpret_cast<const float4*>(src + sub * 8);
    const float4 v1 = *reinterpret_cast<const float4*>(src + sub * 8 + 4);
    float ss = v0.x*v0.x + v0.y*v0.y + v0.z*v0.z + v0.w*v0.w
             + v1.x*v1.x + v1.y*v1.y + v1.z*v1.z + v1.w*v1.w;
    #pragma unroll
    for (int off = 1; off <= 8; off <<= 1) ss += __shfl_xor(ss, off);

    const float scale = qmask[row] ? (1.0f / fmaxf(sqrtf(ss), 1e-12f)) : 0.0f;

    short8 o;
    const float f[8] = {v0.x, v0.y, v0.z, v0.w, v1.x, v1.y, v1.z, v1.w};
    #pragma unroll
    for (int j = 0; j < 8; ++j) {
        __hip_bfloat16 b = __float2bfloat16(f[j] * scale);
        o[j] = *reinterpret_cast<short*>(&b);
    }
    *reinterpret_cast<short8*>(qn + (size_t)row * DIM + sub * 8) = o;
}

// ---------------- Kernel 2: fused D-normalize + chamfer, 1 block/CU, 1 round --------
// Grid 256 = (bd in 0..63) x (g in 0..3); block owns bd's doc panel and bq in
// [g*16, g*16+16). Phase 0: normalize D panel f32 -> bf16 into LDS, XOR-swizzled
// (chunk' = chunk ^ (row&7)) for conflict-free ds_read_b128. Then 4 MT-groups of
// {MFMA vs LDS-D, A-frags from global qn (L1/L2-resident), chamfer reductions}.
// MFMA 16x16x32 bf16: A lane row=l&15, k=(l>>4)*8+j; C/D col=l&15, row=(l>>4)*4+reg.
// Mask quirk: pair (bq,bd) gated by qm[bq,t] && dm[bq,s] (doc mask via QUERY batch);
// doc embeddings themselves zeroed by dm[bd,s] in phase 0.
__global__ __launch_bounds__(256) void chamfer_fused(
    const float* __restrict__ d,
    const __hip_bfloat16* __restrict__ qn,
    const int* __restrict__ qmask,
    const int* __restrict__ dmask,
    float* __restrict__ out)
{
    __shared__ __hip_bfloat16 ldsD[ND * DIM];        // 64 KB
    __shared__ float s_cmax[MT][ND];                 // 4 KB
    __shared__ float s_rmaxT[MT][NQ][4];             // 2 KB

    const int bd  = blockIdx.x & 63;
    const int g   = blockIdx.x >> 6;
    const int tid = threadIdx.x;
    const int w   = tid >> 6;
    const int l   = tid & 63;
    const int lr  = l & 15;
    const int lk  = l >> 4;

    // ---- Phase 0: normalize this bd's doc panel into LDS (bf16, swizzled) ----
    {
        const float* Dsrc = d + (size_t)bd * ND * DIM;
        const int sub = tid & 15;
        const int rb  = tid >> 4;
        #pragma unroll
        for (int it = 0; it < 16; ++it) {
            const int row = it * 16 + rb;                 // 0..255
            const float4 v0 = *reinterpret_cast<const float4*>(Dsrc + row * DIM + sub * 8);
            const float4 v1 = *reinterpret_cast<const float4*>(Dsrc + row * DIM + sub * 8 + 4);
            float ss = v0.x*v0.x + v0.y*v0.y + v0.z*v0.z + v0.w*v0.w
                     + v1.x*v1.x + v1.y*v1.y + v1.z*v1.z + v1.w*v1.w;
            #pragma unroll
            for (int off = 1; off <= 8; off <<= 1) ss += __shfl_xor(ss, off);
            const float scale = dmask[bd * ND + row] ? (1.0f / fmaxf(sqrtf(ss), 1e-12f)) : 0.0f;
            short8 o;
            const float f[8] = {v0.x, v0.y, v0.z, v0.w, v1.x, v1.y, v1.z, v1.w};
            #pragma unroll
            for (int j = 0; j < 8; ++j) {
                __hip_bfloat16 b = __float2bfloat16(f[j] * scale);
                o[j] = *reinterpret_cast<short*>(&b);
            }
            *reinterpret_cast<short8*>((char*)&ldsD[0] + row * 256 + ((sub ^ (row & 7)) << 4)) = o;
        }
    }
    __syncthreads();

    // ---- 4 MT-groups: bq in [g*16 + mm*4, +4) ----
    #pragma unroll 1
    for (int mm = 0; mm < 4; ++mm) {
        const int bq0 = g * 16 + mm * MT;

        // masks (doc-gate indexed by bq — reference broadcast quirk)
        int4 qm4[MT][2];
        int  dmv[MT][4];
        #pragma unroll
        for (int m = 0; m < MT; ++m) {
            #pragma unroll
            for (int mi = 0; mi < 2; ++mi)
                qm4[m][mi] = *reinterpret_cast<const int4*>(&qmask[(bq0 + m) * NQ + mi * 16 + lk * 4]);
            #pragma unroll
            for (int ni = 0; ni < 4; ++ni)
                dmv[m][ni] = dmask[(bq0 + m) * ND + w * 64 + ni * 16 + lr];
        }

        // MFMA: B-frags from LDS (swizzled), A-frags from global qn
        f32x4 acc[MT][2][4] = {};
        #pragma unroll
        for (int kk = 0; kk < 4; ++kk) {
            const int k0   = kk * 32 + lk * 8;
            const int cL   = kk * 4 + lk;                 // logical 16B chunk
            bf16x8 bfr[4];
            #pragma unroll
            for (int ni = 0; ni < 4; ++ni) {
                const int rowd = w * 64 + ni * 16 + lr;
                bfr[ni] = *reinterpret_cast<const bf16x8*>(
                    (const char*)&ldsD[0] + rowd * 256 + ((cL ^ (rowd & 7)) << 4));
            }
            #pragma unroll
            for (int m = 0; m < MT; ++m) {
                const __hip_bfloat16* Q = qn + (size_t)(bq0 + m) * (NQ * DIM);
                #pragma unroll
                for (int mi = 0; mi < 2; ++mi) {
                    const bf16x8 a = *reinterpret_cast<const bf16x8*>(Q + (mi * 16 + lr) * DIM + k0);
                    #pragma unroll
                    for (int ni = 0; ni < 4; ++ni)
                        acc[m][mi][ni] = __builtin_amdgcn_mfma_f32_16x16x32_bf16(a, bfr[ni], acc[m][mi][ni], 0, 0, 0);
                }
            }
        }

        // per-wave partial maxes -> LDS
        #pragma unroll
        for (int m = 0; m < MT; ++m) {
            float rmax[2][4];
            float cmax[4];
            #pragma unroll
            for (int ni = 0; ni < 4; ++ni) cmax[ni] = NEG_INF_F;
            #pragma unroll
            for (int mi = 0; mi < 2; ++mi) {
                const int qmr[4] = {qm4[m][mi].x, qm4[m][mi].y, qm4[m][mi].z, qm4[m][mi].w};
                #pragma unroll
                for (int r = 0; r < 4; ++r) {
                    float rm = NEG_INF_F;
                    #pragma unroll
                    for (int ni = 0; ni < 4; ++ni) {
                        const float v = (qmr[r] && dmv[m][ni]) ? acc[m][mi][ni][r] : NEG_INF_F;
                        rm = fmaxf(rm, v);
                        cmax[ni] = fmaxf(cmax[ni], v);
                    }
                    rmax[mi][r] = rm;
                }
            }
            #pragma unroll
            for (int ni = 0; ni < 4; ++ni) {
                cmax[ni] = fmaxf(cmax[ni], __shfl_xor(cmax[ni], 16));
                cmax[ni] = fmaxf(cmax[ni], __shfl_xor(cmax[ni], 32));
            }
            if (lk == 0) {
                #pragma unroll
                for (int ni = 0; ni < 4; ++ni)
                    s_cmax[m][w * 64 + ni * 16 + lr] = cmax[ni];
            }
            #pragma unroll
            for (int mi = 0; mi < 2; ++mi)
                #pragma unroll
                for (int r = 0; r < 4; ++r) {
                    #pragma unroll
                    for (int off = 1; off <= 8; off <<= 1)
                        rmax[mi][r] = fmaxf(rmax[mi][r], __shfl_xor(rmax[mi][r], off));
                }
            if (lr == 0) {
                #pragma unroll
                for (int mi = 0; mi < 2; ++mi)
                    #pragma unroll
                    for (int r = 0; r < 4; ++r)
                        s_rmaxT[m][mi * 16 + lk * 4 + r][w] = rmax[mi][r];
            }
        }
        __syncthreads();

        // tail: wave w finishes bq = bq0 + w
        {
            const int m = w;
            const float4 cm = *reinterpret_cast<const float4*>(&s_cmax[m][l * 4]);
            float sd = 0.0f, cd = 0.0f;
            if (cm.x > VALID_F) { sd += cm.x; cd += 1.0f; }
            if (cm.y > VALID_F) { sd += cm.y; cd += 1.0f; }
            if (cm.z > VALID_F) { sd += cm.z; cd += 1.0f; }
            if (cm.w > VALID_F) { sd += cm.w; cd += 1.0f; }
            float sq = 0.0f, cq = 0.0f;
            if (l < NQ) {
                const float4 rm4 = *reinterpret_cast<const float4*>(&s_rmaxT[m][l][0]);
                const float v = fmaxf(fmaxf(rm4.x, rm4.y), fmaxf(rm4.z, rm4.w));
                if (v > VALID_F) { sq = v; cq = 1.0f; }
            }
            #pragma unroll
            for (int off = 1; off <= 32; off <<= 1) {
                sd += __shfl_xor(sd, off);
                cd += __shfl_xor(cd, off);
                sq += __shfl_xor(sq, off);
                cq += __shfl_xor(cq, off);
            }
            if (l == 0) {
                const float q2d = sq / fmaxf(cq, 1.0f);
                const float d2q = sd / fmaxf(cd, 1.0f);
                out[(bq0 + m) * B_ + bd] = 0.5f * (q2d + d2q);
            }
        }
        __syncthreads();   // protect s_cmax/s_rmaxT reuse by next mm
    }
}

extern "C" void kernel_launch(void* const* d_in, const int* in_sizes, int n_in,
                              void* d_out, int out_size, void* d_ws, size_t ws_size,
                              hipStream_t stream) {
    const float* q  = (const float*)d_in[0];   // [64][32][128] f32
    const int*   qm = (const int*)d_in[1];     // [64][32] i32
    const float* d  = (const float*)d_in[2];   // [64][256][128] f32
    const int*   dm = (const int*)d_in[3];     // [64][256] i32
    float* out = (float*)d_out;                // [64][64] f32

    __hip_bfloat16* qn = (__hip_bfloat16*)d_ws;   // 2048*128 bf16 = 512 KB, linear

    qnorm<<<(B_ * NQ) / 16, 256, 0, stream>>>(q, qm, qn);
    chamfer_fused<<<B_ * 4, 256, 0, stream>>>(d, qn, qm, dm, out);
}

// Round 6
// 102.367 us; speedup vs baseline: 1.1334x; 1.1334x over previous
//
#include <hip/hip_runtime.h>
#include <hip/hip_bf16.h>
#include <stdint.h>

typedef short bf16x8 __attribute__((ext_vector_type(8)));
typedef short short8 __attribute__((ext_vector_type(8)));
typedef float f32x4 __attribute__((ext_vector_type(4)));

#define B_   64
#define NQ   32
#define ND   256
#define DIM  128
#define MT   4          // bq per MFMA group
#define NEG_INF_F (-1.0e9f)
#define VALID_F   (-1.0e8f)

// Single fused kernel. Grid 256 = (bd in 0..63) x (g in 0..3), 512 threads (8 waves).
// Block owns doc batch bd and query batches [g*16, g*16+16).
//  Phase D: normalize bd's doc panel f32->bf16 into LDS (XOR-swizzled chunks).
//  Per mm-group (4 bq): stage+normalize 128 q rows into LDS (swizzled), MFMA with
//  A and B both from LDS (wave w owns doc cols [w*32,w*32+32)), chamfer reductions.
// MFMA 16x16x32 bf16: A lane row=l&15, k=(l>>4)*8+j; C/D col=l&15, row=(l>>4)*4+reg.
// Swizzle: 16B chunk c of row r stored at chunk c ^ (r&7)  => conflict-free b128.
// Mask quirk: pair (bq,bd) gated by qm[bq,t] && dm[bq,s] (doc mask via QUERY batch);
// doc embeddings themselves zeroed by dm[bd,s] in phase D.
// No d_ws usage at all.
__global__ __launch_bounds__(512, 2) void chamfer_one(
    const float* __restrict__ q,
    const int* __restrict__ qmask,
    const float* __restrict__ d,
    const int* __restrict__ dmask,
    float* __restrict__ out)
{
    __shared__ __hip_bfloat16 ldsD[ND * DIM];        // 64 KB
    __shared__ __hip_bfloat16 ldsQ[4 * NQ * DIM];    // 32 KB (one mm-group of Q)
    __shared__ float s_cmax[MT][ND];                 // 4 KB
    __shared__ float s_rmaxT[MT][NQ][8];             // 4 KB

    const int bd  = blockIdx.x & 63;
    const int g   = blockIdx.x >> 6;
    const int tid = threadIdx.x;
    const int w   = tid >> 6;          // wave 0..7
    const int l   = tid & 63;
    const int lr  = l & 15;
    const int lk  = l >> 4;
    const int grp = tid >> 4;          // 16-lane group 0..31
    const int sub = tid & 15;

    // ---- Phase D: normalize doc panel into LDS (8 iterations of 32 rows) ----
    {
        const float* Dsrc = d + (size_t)bd * ND * DIM;
        #pragma unroll
        for (int it = 0; it < 8; ++it) {
            const int row = it * 32 + grp;            // 0..255
            const float4 v0 = *reinterpret_cast<const float4*>(Dsrc + row * DIM + sub * 8);
            const float4 v1 = *reinterpret_cast<const float4*>(Dsrc + row * DIM + sub * 8 + 4);
            float ss = v0.x*v0.x + v0.y*v0.y + v0.z*v0.z + v0.w*v0.w
                     + v1.x*v1.x + v1.y*v1.y + v1.z*v1.z + v1.w*v1.w;
            #pragma unroll
            for (int off = 1; off <= 8; off <<= 1) ss += __shfl_xor(ss, off);
            const float scale = dmask[bd * ND + row] ? (1.0f / fmaxf(sqrtf(ss), 1e-12f)) : 0.0f;
            short8 o;
            const float f[8] = {v0.x, v0.y, v0.z, v0.w, v1.x, v1.y, v1.z, v1.w};
            #pragma unroll
            for (int j = 0; j < 8; ++j) {
                __hip_bfloat16 b = __float2bfloat16(f[j] * scale);
                o[j] = *reinterpret_cast<short*>(&b);
            }
            *reinterpret_cast<short8*>((char*)&ldsD[0] + row * 256 + (((sub ^ (row & 7)) & 15) << 4)) = o;
        }
    }

    // ---- 4 mm-groups ----
    #pragma unroll 1
    for (int mm = 0; mm < 4; ++mm) {
        const int bq0 = g * 16 + mm * MT;

        // stage+normalize 128 q rows (4 iterations of 32 rows) into ldsQ
        {
            const float* Qsrc = q + (size_t)bq0 * NQ * DIM;
            #pragma unroll
            for (int it = 0; it < 4; ++it) {
                const int row = it * 32 + grp;        // 0..127 (= m*32 + t)
                const float4 v0 = *reinterpret_cast<const float4*>(Qsrc + row * DIM + sub * 8);
                const float4 v1 = *reinterpret_cast<const float4*>(Qsrc + row * DIM + sub * 8 + 4);
                float ss = v0.x*v0.x + v0.y*v0.y + v0.z*v0.z + v0.w*v0.w
                         + v1.x*v1.x + v1.y*v1.y + v1.z*v1.z + v1.w*v1.w;
                #pragma unroll
                for (int off = 1; off <= 8; off <<= 1) ss += __shfl_xor(ss, off);
                const float scale = qmask[bq0 * NQ + row] ? (1.0f / fmaxf(sqrtf(ss), 1e-12f)) : 0.0f;
                short8 o;
                const float f[8] = {v0.x, v0.y, v0.z, v0.w, v1.x, v1.y, v1.z, v1.w};
                #pragma unroll
                for (int j = 0; j < 8; ++j) {
                    __hip_bfloat16 b = __float2bfloat16(f[j] * scale);
                    o[j] = *reinterpret_cast<short*>(&b);
                }
                *reinterpret_cast<short8*>((char*)&ldsQ[0] + row * 256 + (((sub ^ (row & 7)) & 15) << 4)) = o;
            }
        }

        // masks (doc-gate indexed by bq — reference broadcast quirk)
        int4 qm4[MT][2];
        int  dmv[MT][2];
        #pragma unroll
        for (int m = 0; m < MT; ++m) {
            #pragma unroll
            for (int mi = 0; mi < 2; ++mi)
                qm4[m][mi] = *reinterpret_cast<const int4*>(&qmask[(bq0 + m) * NQ + mi * 16 + lk * 4]);
            #pragma unroll
            for (int ni = 0; ni < 2; ++ni)
                dmv[m][ni] = dmask[(bq0 + m) * ND + w * 32 + ni * 16 + lr];
        }

        __syncthreads();   // ldsQ ready (and previous tail done with s_* / ldsQ)

        // MFMA: wave w owns doc cols [w*32, w*32+32); A and B from swizzled LDS
        f32x4 acc[MT][2][2] = {};
        #pragma unroll
        for (int kk = 0; kk < 4; ++kk) {
            const int cL = kk * 4 + lk;               // logical 16B chunk 0..15
            bf16x8 bfr[2];
            #pragma unroll
            for (int ni = 0; ni < 2; ++ni) {
                const int rowd = w * 32 + ni * 16 + lr;
                bfr[ni] = *reinterpret_cast<const bf16x8*>(
                    (const char*)&ldsD[0] + rowd * 256 + (((cL ^ (rowd & 7)) & 15) << 4));
            }
            #pragma unroll
            for (int m = 0; m < MT; ++m) {
                #pragma unroll
                for (int mi = 0; mi < 2; ++mi) {
                    const int rowq = m * NQ + mi * 16 + lr;
                    const bf16x8 a = *reinterpret_cast<const bf16x8*>(
                        (const char*)&ldsQ[0] + rowq * 256 + (((cL ^ (rowq & 7)) & 15) << 4));
                    #pragma unroll
                    for (int ni = 0; ni < 2; ++ni)
                        acc[m][mi][ni] = __builtin_amdgcn_mfma_f32_16x16x32_bf16(a, bfr[ni], acc[m][mi][ni], 0, 0, 0);
                }
            }
        }

        // per-wave partial maxes -> LDS
        #pragma unroll
        for (int m = 0; m < MT; ++m) {
            float rmax[2][4];
            float cmax[2];
            #pragma unroll
            for (int ni = 0; ni < 2; ++ni) cmax[ni] = NEG_INF_F;
            #pragma unroll
            for (int mi = 0; mi < 2; ++mi) {
                const int qmr[4] = {qm4[m][mi].x, qm4[m][mi].y, qm4[m][mi].z, qm4[m][mi].w};
                #pragma unroll
                for (int r = 0; r < 4; ++r) {
                    float rm = NEG_INF_F;
                    #pragma unroll
                    for (int ni = 0; ni < 2; ++ni) {
                        const float v = (qmr[r] && dmv[m][ni]) ? acc[m][mi][ni][r] : NEG_INF_F;
                        rm = fmaxf(rm, v);
                        cmax[ni] = fmaxf(cmax[ni], v);
                    }
                    rmax[mi][r] = rm;
                }
            }
            // col max over all 32 rows (lanes differing in lk)
            #pragma unroll
            for (int ni = 0; ni < 2; ++ni) {
                cmax[ni] = fmaxf(cmax[ni], __shfl_xor(cmax[ni], 16));
                cmax[ni] = fmaxf(cmax[ni], __shfl_xor(cmax[ni], 32));
            }
            if (lk == 0) {
                #pragma unroll
                for (int ni = 0; ni < 2; ++ni)
                    s_cmax[m][w * 32 + ni * 16 + lr] = cmax[ni];
            }
            // row max over this wave's 32 cols (lanes differing in lr)
            #pragma unroll
            for (int mi = 0; mi < 2; ++mi)
                #pragma unroll
                for (int r = 0; r < 4; ++r) {
                    #pragma unroll
                    for (int off = 1; off <= 8; off <<= 1)
                        rmax[mi][r] = fmaxf(rmax[mi][r], __shfl_xor(rmax[mi][r], off));
                }
            if (lr == 0) {
                #pragma unroll
                for (int mi = 0; mi < 2; ++mi)
                    #pragma unroll
                    for (int r = 0; r < 4; ++r)
                        s_rmaxT[m][mi * 16 + lk * 4 + r][w] = rmax[mi][r];
            }
        }
        __syncthreads();

        // tail: waves 0..3 finish bq = bq0 + w  (waves 4..7 fall through to next stageQ)
        if (w < MT) {
            const int m = w;
            const float4 cm = *reinterpret_cast<const float4*>(&s_cmax[m][l * 4]);
            float sd = 0.0f, cd = 0.0f;
            if (cm.x > VALID_F) { sd += cm.x; cd += 1.0f; }
            if (cm.y > VALID_F) { sd += cm.y; cd += 1.0f; }
            if (cm.z > VALID_F) { sd += cm.z; cd += 1.0f; }
            if (cm.w > VALID_F) { sd += cm.w; cd += 1.0f; }
            float sq = 0.0f, cq = 0.0f;
            if (l < NQ) {
                const float4 a = *reinterpret_cast<const float4*>(&s_rmaxT[m][l][0]);
                const float4 b = *reinterpret_cast<const float4*>(&s_rmaxT[m][l][4]);
                const float v = fmaxf(fmaxf(fmaxf(a.x, a.y), fmaxf(a.z, a.w)),
                                      fmaxf(fmaxf(b.x, b.y), fmaxf(b.z, b.w)));
                if (v > VALID_F) { sq = v; cq = 1.0f; }
            }
            #pragma unroll
            for (int off = 1; off <= 32; off <<= 1) {
                sd += __shfl_xor(sd, off);
                cd += __shfl_xor(cd, off);
                sq += __shfl_xor(sq, off);
                cq += __shfl_xor(cq, off);
            }
            if (l == 0) {
                const float q2d = sq / fmaxf(cq, 1.0f);
                const float d2q = sd / fmaxf(cd, 1.0f);
                out[(bq0 + m) * B_ + bd] = 0.5f * (q2d + d2q);
            }
        }
        // NOTE: no barrier here. Next iteration's stageQ writes ldsQ (all waves done
        // reading it before the post-MFMA barrier above); the pre-MFMA barrier next
        // iteration orders tail's s_* reads vs next partial writes.
    }
}

extern "C" void kernel_launch(void* const* d_in, const int* in_sizes, int n_in,
                              void* d_out, int out_size, void* d_ws, size_t ws_size,
                              hipStream_t stream) {
    const float* q  = (const float*)d_in[0];   // [64][32][128] f32
    const int*   qm = (const int*)d_in[1];     // [64][32] i32
    const float* d  = (const float*)d_in[2];   // [64][256][128] f32
    const int*   dm = (const int*)d_in[3];     // [64][256] i32
    float* out = (float*)d_out;                // [64][64] f32

    chamfer_one<<<B_ * 4, 512, 0, stream>>>(q, qm, d, dm, out);
}

// Round 8
// 97.515 us; speedup vs baseline: 1.1898x; 1.0498x over previous
//
#include <hip/hip_runtime.h>
#include <hip/hip_bf16.h>
#include <stdint.h>

typedef short bf16x8 __attribute__((ext_vector_type(8)));
typedef short short8 __attribute__((ext_vector_type(8)));
typedef float f32x4 __attribute__((ext_vector_type(4)));

#define B_   64
#define NQ   32
#define ND   256
#define DIM  128
#define MT   4          // bq per MFMA group
#define NEG_INF_F (-1.0e9f)
#define VALID_F   (-1.0e8f)

// Single fused kernel. Grid 256 = (bd in 0..63) x (g in 0..3), 512 threads (8 waves).
// Effective clock during timing is ~1 GHz (DVFS depressed by the harness's 256MB
// re-poison fill each iteration) -> minimize CYCLES, maximize MLP on the
// compulsory 8MB d fetch (L3 is swept by the fill every iteration).
//  Phase D: 16 hoisted dwordx4 loads/wave (full MLP), then normalize f32->bf16
//  into LDS, XOR-swizzled (chunk c of row r at c ^ (r&7)) => conflict-free b128.
//  Per mm-group (4 bq): 8 hoisted Q loads, normalize into ldsQ (swizzled), MFMA
//  (wave w owns doc cols [w*32,w*32+32)), chamfer reductions via shuffle trees.
// MFMA 16x16x32 bf16: A lane row=l&15, k=(l>>4)*8+j; C/D col=l&15, row=(l>>4)*4+reg.
// Masking is ARITHMETIC: tok = acc + qneg[t] + dneg[s] with {0,-1e9} terms;
// masked tok <= -1e9+1 < VALID_F, valid tok = sim exactly (adds of 0.0).
// Mask quirk: pair (bq,bd) gated by qm[bq,t] && dm[bq,s] (doc mask via QUERY
// batch); doc embeddings themselves zeroed by dm[bd,s] in phase D.
__global__ __launch_bounds__(512, 2) void chamfer_one(
    const float* __restrict__ q,
    const int* __restrict__ qmask,
    const float* __restrict__ d,
    const int* __restrict__ dmask,
    float* __restrict__ out)
{
    __shared__ __hip_bfloat16 ldsD[ND * DIM];        // 64 KB
    __shared__ __hip_bfloat16 ldsQ[4 * NQ * DIM];    // 32 KB (one mm-group of Q)
    __shared__ float s_cmax[MT][ND];                 // 4 KB
    __shared__ float s_rmaxT[MT][NQ][8];             // 4 KB

    const int bd  = blockIdx.x & 63;
    const int g   = blockIdx.x >> 6;
    const int tid = threadIdx.x;
    const int w   = tid >> 6;          // wave 0..7
    const int l   = tid & 63;
    const int lr  = l & 15;
    const int lk  = l >> 4;
    const int grp = tid >> 4;          // 16-lane group 0..31
    const int sub = tid & 15;

    const float* Dsrc = d + (size_t)bd * ND * DIM;

    // ---- issue ALL phase-D loads back-to-back (16 dwordx4 + 8 mask words) ----
    float4 dva[8], dvb[8];
    int    dmk[8];
    #pragma unroll
    for (int it = 0; it < 8; ++it) {
        const int row = it * 32 + grp;            // 0..255
        dva[it] = *reinterpret_cast<const float4*>(Dsrc + row * DIM + sub * 8);
        dvb[it] = *reinterpret_cast<const float4*>(Dsrc + row * DIM + sub * 8 + 4);
        dmk[it] = dmask[bd * ND + row];
    }

    // ---- issue mm=0's Q loads too (overlap with D compute) ----
    float4 qva[4], qvb[4];
    int    qmk[4];
    {
        const float* Qsrc = q + (size_t)(g * 16) * NQ * DIM;
        #pragma unroll
        for (int it = 0; it < 4; ++it) {
            const int row = it * 32 + grp;        // 0..127
            qva[it] = *reinterpret_cast<const float4*>(Qsrc + row * DIM + sub * 8);
            qvb[it] = *reinterpret_cast<const float4*>(Qsrc + row * DIM + sub * 8 + 4);
            qmk[it] = qmask[(g * 16) * NQ + row];
        }
    }

    // ---- Phase D compute: normalize doc panel into LDS (swizzled) ----
    #pragma unroll
    for (int it = 0; it < 8; ++it) {
        const int row = it * 32 + grp;
        const float4 v0 = dva[it], v1 = dvb[it];
        float ss = v0.x*v0.x + v0.y*v0.y + v0.z*v0.z + v0.w*v0.w
                 + v1.x*v1.x + v1.y*v1.y + v1.z*v1.z + v1.w*v1.w;
        #pragma unroll
        for (int off = 1; off <= 8; off <<= 1) ss += __shfl_xor(ss, off);
        const float scale = dmk[it] ? (1.0f / fmaxf(sqrtf(ss), 1e-12f)) : 0.0f;
        short8 o;
        const float f[8] = {v0.x, v0.y, v0.z, v0.w, v1.x, v1.y, v1.z, v1.w};
        #pragma unroll
        for (int j = 0; j < 8; ++j) {
            __hip_bfloat16 b = __float2bfloat16(f[j] * scale);
            o[j] = *reinterpret_cast<short*>(&b);
        }
        *reinterpret_cast<short8*>((char*)&ldsD[0] + row * 256 + ((sub ^ (row & 7)) << 4)) = o;
    }

    // ---- 4 mm-groups ----
    #pragma unroll 1
    for (int mm = 0; mm < 4; ++mm) {
        const int bq0 = g * 16 + mm * MT;

        if (mm > 0) {   // mm=0's loads already in flight
            const float* Qsrc = q + (size_t)bq0 * NQ * DIM;
            #pragma unroll
            for (int it = 0; it < 4; ++it) {
                const int row = it * 32 + grp;
                qva[it] = *reinterpret_cast<const float4*>(Qsrc + row * DIM + sub * 8);
                qvb[it] = *reinterpret_cast<const float4*>(Qsrc + row * DIM + sub * 8 + 4);
                qmk[it] = qmask[bq0 * NQ + row];
            }
        }

        // normalize 128 q rows into ldsQ (swizzled)
        #pragma unroll
        for (int it = 0; it < 4; ++it) {
            const int row = it * 32 + grp;        // 0..127
            const float4 v0 = qva[it], v1 = qvb[it];
            float ss = v0.x*v0.x + v0.y*v0.y + v0.z*v0.z + v0.w*v0.w
                     + v1.x*v1.x + v1.y*v1.y + v1.z*v1.z + v1.w*v1.w;
            #pragma unroll
            for (int off = 1; off <= 8; off <<= 1) ss += __shfl_xor(ss, off);
            const float scale = qmk[it] ? (1.0f / fmaxf(sqrtf(ss), 1e-12f)) : 0.0f;
            short8 o;
            const float f[8] = {v0.x, v0.y, v0.z, v0.w, v1.x, v1.y, v1.z, v1.w};
            #pragma unroll
            for (int j = 0; j < 8; ++j) {
                __hip_bfloat16 b = __float2bfloat16(f[j] * scale);
                o[j] = *reinterpret_cast<short*>(&b);
            }
            *reinterpret_cast<short8*>((char*)&ldsQ[0] + row * 256 + ((sub ^ (row & 7)) << 4)) = o;
        }

        // gate masks -> NEG_INF addends (doc-gate indexed by bq — reference quirk)
        float qneg[MT][2][4];
        float dneg[MT][2];
        #pragma unroll
        for (int m = 0; m < MT; ++m) {
            #pragma unroll
            for (int mi = 0; mi < 2; ++mi) {
                const int4 qi = *reinterpret_cast<const int4*>(&qmask[(bq0 + m) * NQ + mi * 16 + lk * 4]);
                qneg[m][mi][0] = qi.x ? 0.0f : NEG_INF_F;
                qneg[m][mi][1] = qi.y ? 0.0f : NEG_INF_F;
                qneg[m][mi][2] = qi.z ? 0.0f : NEG_INF_F;
                qneg[m][mi][3] = qi.w ? 0.0f : NEG_INF_F;
            }
            #pragma unroll
            for (int ni = 0; ni < 2; ++ni)
                dneg[m][ni] = dmask[(bq0 + m) * ND + w * 32 + ni * 16 + lr] ? 0.0f : NEG_INF_F;
        }

        __syncthreads();   // ldsD (mm=0) + ldsQ ready; prev tail done with s_*

        // MFMA: wave w owns doc cols [w*32, w*32+32); A and B from swizzled LDS
        f32x4 acc[MT][2][2] = {};
        #pragma unroll
        for (int kk = 0; kk < 4; ++kk) {
            const int cL = kk * 4 + lk;               // logical 16B chunk 0..15
            bf16x8 bfr[2];
            #pragma unroll
            for (int ni = 0; ni < 2; ++ni) {
                const int rowd = w * 32 + ni * 16 + lr;
                bfr[ni] = *reinterpret_cast<const bf16x8*>(
                    (const char*)&ldsD[0] + rowd * 256 + ((cL ^ (rowd & 7)) << 4));
            }
            #pragma unroll
            for (int m = 0; m < MT; ++m) {
                #pragma unroll
                for (int mi = 0; mi < 2; ++mi) {
                    const int rowq = m * NQ + mi * 16 + lr;
                    const bf16x8 a = *reinterpret_cast<const bf16x8*>(
                        (const char*)&ldsQ[0] + rowq * 256 + ((cL ^ (rowq & 7)) << 4));
                    #pragma unroll
                    for (int ni = 0; ni < 2; ++ni)
                        acc[m][mi][ni] = __builtin_amdgcn_mfma_f32_16x16x32_bf16(a, bfr[ni], acc[m][mi][ni], 0, 0, 0);
                }
            }
        }

        // per-wave partial maxes (arithmetic masking) -> LDS
        #pragma unroll
        for (int m = 0; m < MT; ++m) {
            float rmax[2][4];
            float cmax[2] = {NEG_INF_F, NEG_INF_F};
            #pragma unroll
            for (int mi = 0; mi < 2; ++mi) {
                #pragma unroll
                for (int r = 0; r < 4; ++r) {
                    const float t0 = acc[m][mi][0][r] + (qneg[m][mi][r] + dneg[m][0]);
                    const float t1 = acc[m][mi][1][r] + (qneg[m][mi][r] + dneg[m][1]);
                    rmax[mi][r] = fmaxf(t0, t1);
                    cmax[0] = fmaxf(cmax[0], t0);
                    cmax[1] = fmaxf(cmax[1], t1);
                }
            }
            // col max over all 32 rows (lanes differing in lk)
            #pragma unroll
            for (int ni = 0; ni < 2; ++ni) {
                cmax[ni] = fmaxf(cmax[ni], __shfl_xor(cmax[ni], 16));
                cmax[ni] = fmaxf(cmax[ni], __shfl_xor(cmax[ni], 32));
            }
            if (lk == 0) {
                #pragma unroll
                for (int ni = 0; ni < 2; ++ni)
                    s_cmax[m][w * 32 + ni * 16 + lr] = cmax[ni];
            }
            // row max over this wave's 32 cols (lanes differing in lr)
            #pragma unroll
            for (int mi = 0; mi < 2; ++mi)
                #pragma unroll
                for (int r = 0; r < 4; ++r) {
                    #pragma unroll
                    for (int off = 1; off <= 8; off <<= 1)
                        rmax[mi][r] = fmaxf(rmax[mi][r], __shfl_xor(rmax[mi][r], off));
                }
            if (lr == 0) {
                #pragma unroll
                for (int mi = 0; mi < 2; ++mi)
                    #pragma unroll
                    for (int r = 0; r < 4; ++r)
                        s_rmaxT[m][mi * 16 + lk * 4 + r][w] = rmax[mi][r];
            }
        }
        __syncthreads();

        // tail: waves 0..3 finish bq = bq0 + w (waves 4..7 fall through to next stageQ)
        if (w < MT) {
            const int m = w;
            const float4 cm = *reinterpret_cast<const float4*>(&s_cmax[m][l * 4]);
            float sd = 0.0f, cd = 0.0f;
            if (cm.x > VALID_F) { sd += cm.x; cd += 1.0f; }
            if (cm.y > VALID_F) { sd += cm.y; cd += 1.0f; }
            if (cm.z > VALID_F) { sd += cm.z; cd += 1.0f; }
            if (cm.w > VALID_F) { sd += cm.w; cd += 1.0f; }
            float sq = 0.0f, cq = 0.0f;
            if (l < NQ) {
                const float4 a = *reinterpret_cast<const float4*>(&s_rmaxT[m][l][0]);
                const float4 b = *reinterpret_cast<const float4*>(&s_rmaxT[m][l][4]);
                const float v = fmaxf(fmaxf(fmaxf(a.x, a.y), fmaxf(a.z, a.w)),
                                      fmaxf(fmaxf(b.x, b.y), fmaxf(b.z, b.w)));
                if (v > VALID_F) { sq = v; cq = 1.0f; }
            }
            #pragma unroll
            for (int off = 1; off <= 32; off <<= 1) {
                sd += __shfl_xor(sd, off);
                cd += __shfl_xor(cd, off);
                sq += __shfl_xor(sq, off);
                cq += __shfl_xor(cq, off);
            }
            if (l == 0) {
                const float q2d = sq / fmaxf(cq, 1.0f);
                const float d2q = sd / fmaxf(cd, 1.0f);
                out[(bq0 + m) * B_ + bd] = 0.5f * (q2d + d2q);
            }
        }
        // no barrier: next stageQ writes ldsQ only after this iteration's 2nd
        // barrier (all MFMA reads done); tail reads s_* which stageQ doesn't touch.
    }
}

extern "C" void kernel_launch(void* const* d_in, const int* in_sizes, int n_in,
                              void* d_out, int out_size, void* d_ws, size_t ws_size,
                              hipStream_t stream) {
    const float* q  = (const float*)d_in[0];   // [64][32][128] f32
    const int*   qm = (const int*)d_in[1];     // [64][32] i32
    const float* d  = (const float*)d_in[2];   // [64][256][128] f32
    const int*   dm = (const int*)d_in[3];     // [64][256] i32
    float* out = (float*)d_out;                // [64][64] f32

    chamfer_one<<<B_ * 4, 512, 0, stream>>>(q, qm, d, dm, out);
}